// Round 1
// baseline (558.524 us; speedup 1.0000x reference)
//
#include <hip/hip_runtime.h>
#include <hip/hip_bf16.h>
#include <math.h>

#define HIDDEN 4096
#define NHEADS 32
#define HDIM 128
#define CLEN 512
#define BATCH 32

// ---------------------------------------------------------------------------
// Projection: Y[b][o] = sum_k X[b][k] * W[o][k]
// X: [32][4096] fp32, W: [4096][4096] row-major (out-feature-major), Y: [32][4096]
// Block = 256 threads. Each block covers 16 output features.
// thread: b = t&31, ol = t>>5 (0..7) -> handles o0+ol and o0+ol+8.
// x chunk staged in LDS (stride 130 floats: b64 reads 2-way-conflict == free).
// W read straight from global: all 32 lanes of a half-wave share the address
// -> hardware broadcast, one fetch; stream is perfectly sequential per row.
// ---------------------------------------------------------------------------
#define KC 128
#define XS_STRIDE 130

__global__ __launch_bounds__(256) void proj_kernel(const float* __restrict__ X,
                                                   const float* __restrict__ W,
                                                   float* __restrict__ Y) {
    __shared__ float xs[BATCH * XS_STRIDE];
    const int t  = threadIdx.x;
    const int b  = t & 31;
    const int ol = t >> 5;                 // 0..7
    const int o0 = blockIdx.x * 16;
    const long o1 = o0 + ol;
    const long o2 = o0 + ol + 8;
    const float* w1 = W + o1 * (long)HIDDEN;
    const float* w2 = W + o2 * (long)HIDDEN;
    float acc1 = 0.f, acc2 = 0.f;

    const int sr = t >> 3;                 // staging row 0..31
    const int sc0 = (t & 7) * 16;          // staging col start

    for (int k0 = 0; k0 < HIDDEN; k0 += KC) {
        __syncthreads();                   // xs reuse protection
        const float* xsrc = X + (size_t)sr * HIDDEN + k0 + sc0;
        float* xdst = xs + sr * XS_STRIDE + sc0;
        #pragma unroll
        for (int j = 0; j < 16; j += 4) {
            float4 v = *reinterpret_cast<const float4*>(xsrc + j);
            *reinterpret_cast<float2*>(xdst + j)     = make_float2(v.x, v.y);
            *reinterpret_cast<float2*>(xdst + j + 2) = make_float2(v.z, v.w);
        }
        __syncthreads();
        const float* xrow = xs + b * XS_STRIDE;
        #pragma unroll
        for (int kk = 0; kk < KC; kk += 4) {
            float2 xa = *reinterpret_cast<const float2*>(xrow + kk);
            float2 xb = *reinterpret_cast<const float2*>(xrow + kk + 2);
            float4 wa = *reinterpret_cast<const float4*>(w1 + k0 + kk);
            float4 wb = *reinterpret_cast<const float4*>(w2 + k0 + kk);
            acc1 += xa.x * wa.x + xa.y * wa.y + xb.x * wa.z + xb.y * wa.w;
            acc2 += xa.x * wb.x + xa.y * wb.y + xb.x * wb.z + xb.y * wb.w;
        }
    }
    Y[(size_t)b * HIDDEN + o1] = acc1;
    Y[(size_t)b * HIDDEN + o2] = acc2;
}

// ---------------------------------------------------------------------------
// Cache attention per (b,h), one block of 256 threads (4 waves).
// scores: per key, 64-lane float2 dot (coalesced 512B row) + shfl reduce.
// softmax in LDS; PV: lane owns dim pair, wave owns a quarter of the keys.
// Fuses the + v_new (new-token softmax over 1 key == 1.0 -> new_out = v_new).
// ---------------------------------------------------------------------------
__global__ __launch_bounds__(256) void attn_kernel(const float* __restrict__ q,    // [32][4096]
                                                   const float* __restrict__ kc,   // [32][32][512][128]
                                                   const float* __restrict__ vc,
                                                   const float* __restrict__ vnew, // [32][4096]
                                                   float* __restrict__ attn_out) { // [32][4096]
    __shared__ float sc[CLEN];
    __shared__ float red[16];
    __shared__ float part[4 * HDIM];
    const int t = threadIdx.x;
    const int w = t >> 6;
    const int l = t & 63;
    const int bh = blockIdx.x;
    const int b = bh >> 5, h = bh & 31;
    const float* qrow = q + (size_t)b * HIDDEN + h * HDIM;
    const float* K = kc + (size_t)bh * CLEN * HDIM;
    const float* V = vc + (size_t)bh * CLEN * HDIM;
    const float scale = 0.088388347648318447f;   // 1/sqrt(128)

    float2 q2 = *reinterpret_cast<const float2*>(qrow + 2 * l);

    // ---- scores ----
    for (int k = w * 128; k < (w + 1) * 128; ++k) {
        float2 k2 = *reinterpret_cast<const float2*>(K + (size_t)k * HDIM + 2 * l);
        float p = q2.x * k2.x + q2.y * k2.y;
        #pragma unroll
        for (int m = 32; m; m >>= 1) p += __shfl_xor(p, m);
        if (l == 0) sc[k] = p * scale;
    }
    __syncthreads();

    // ---- softmax ----
    float s1 = sc[t], s2 = sc[t + 256];
    float mx = fmaxf(s1, s2);
    #pragma unroll
    for (int m = 32; m; m >>= 1) mx = fmaxf(mx, __shfl_xor(mx, m));
    if (l == 0) red[w] = mx;
    __syncthreads();
    mx = fmaxf(fmaxf(red[0], red[1]), fmaxf(red[2], red[3]));
    float e1 = __expf(s1 - mx), e2 = __expf(s2 - mx);
    sc[t] = e1; sc[t + 256] = e2;
    float es = e1 + e2;
    #pragma unroll
    for (int m = 32; m; m >>= 1) es += __shfl_xor(es, m);
    if (l == 0) red[8 + w] = es;
    __syncthreads();
    const float inv = 1.0f / (red[8] + red[9] + red[10] + red[11]);

    // ---- PV ----
    float2 acc = make_float2(0.f, 0.f);
    for (int k = w * 128; k < (w + 1) * 128; ++k) {
        float2 v2 = *reinterpret_cast<const float2*>(V + (size_t)k * HDIM + 2 * l);
        float p = sc[k];
        acc.x += p * v2.x;
        acc.y += p * v2.y;
    }
    *reinterpret_cast<float2*>(&part[w * HDIM + 2 * l]) = acc;
    __syncthreads();
    if (t < 64) {
        float2 r = make_float2(0.f, 0.f);
        #pragma unroll
        for (int ww = 0; ww < 4; ++ww) {
            float2 p2 = *reinterpret_cast<const float2*>(&part[ww * HDIM + 2 * t]);
            r.x += p2.x; r.y += p2.y;
        }
        float2 vn = *reinterpret_cast<const float2*>(vnew + (size_t)b * HIDDEN + h * HDIM + 2 * t);
        float2 o;
        o.x = r.x * inv + vn.x;
        o.y = r.y * inv + vn.y;
        *reinterpret_cast<float2*>(attn_out + (size_t)b * HIDDEN + h * HDIM + 2 * t) = o;
    }
}

extern "C" void kernel_launch(void* const* d_in, const int* in_sizes, int n_in,
                              void* d_out, int out_size, void* d_ws, size_t ws_size,
                              hipStream_t stream) {
    const float* x  = (const float*)d_in[0];
    const float* kc = (const float*)d_in[1];
    const float* vc = (const float*)d_in[2];
    const float* wq = (const float*)d_in[3];
    // d_in[4] (wk) unused: softmax over a single new key is exactly 1.0
    const float* wv = (const float*)d_in[5];
    const float* wo = (const float*)d_in[6];
    float* out = (float*)d_out;

    float* q    = (float*)d_ws;                       // 32*4096 fp32
    float* vnew = q + BATCH * HIDDEN;                 // 32*4096 fp32
    float* attn = vnew + BATCH * HIDDEN;              // 32*4096 fp32

    proj_kernel<<<HIDDEN / 16, 256, 0, stream>>>(x, wq, q);
    proj_kernel<<<HIDDEN / 16, 256, 0, stream>>>(x, wv, vnew);
    attn_kernel<<<BATCH * NHEADS, 256, 0, stream>>>(q, kc, vc, vnew, attn);
    proj_kernel<<<HIDDEN / 16, 256, 0, stream>>>(attn, wo, out);
}

// Round 2
// 409.721 us; speedup vs baseline: 1.3632x; 1.3632x over previous
//
#include <hip/hip_runtime.h>
#include <hip/hip_bf16.h>

#define HIDDEN 4096
#define NHEADS 32
#define HDIM 128
#define CLEN 512
#define BATCH 32
#define KC 128
#define XS_STRIDE 130
#define KSPLIT 4
#define KSLICE (HIDDEN / KSPLIT)   // 1024

// ---------------------------------------------------------------------------
// Projection body: Y[b][o] += sum over k-slice of X[b][k] * W[o][k]
// block = 256 threads (4 waves): b = t&31, ol = t>>5 -> features o0+ol, o0+ol+8.
// Split-K=4 across blocks, partials merged with fp32 atomicAdd (Y pre-zeroed).
// x chunk staged in LDS (stride 130 -> float2 reads are 2-way = free).
// W read as broadcast float4 (lanes of a half-wave share the address).
// ---------------------------------------------------------------------------
__device__ __forceinline__ void proj_body(const float* __restrict__ X,
                                          const float* __restrict__ W,
                                          float* __restrict__ Y,
                                          int fb, int ks) {
    __shared__ float xs[BATCH * XS_STRIDE];
    const int t  = threadIdx.x;
    const int b  = t & 31;
    const int ol = t >> 5;
    const long o1 = fb * 16 + ol;
    const long o2 = fb * 16 + ol + 8;
    const float* w1 = W + o1 * (long)HIDDEN;
    const float* w2 = W + o2 * (long)HIDDEN;
    float a1 = 0.f, a2 = 0.f, a3 = 0.f, a4 = 0.f;   // split chains
    const int sr  = t >> 3;
    const int sc0 = (t & 7) * 16;
    const int kend = ks * KSLICE + KSLICE;
    for (int k0 = ks * KSLICE; k0 < kend; k0 += KC) {
        __syncthreads();
        const float* xsrc = X + (size_t)sr * HIDDEN + k0 + sc0;
        float* xdst = xs + sr * XS_STRIDE + sc0;
        #pragma unroll
        for (int j = 0; j < 16; j += 4) {
            float4 v = *reinterpret_cast<const float4*>(xsrc + j);
            *reinterpret_cast<float2*>(xdst + j)     = make_float2(v.x, v.y);
            *reinterpret_cast<float2*>(xdst + j + 2) = make_float2(v.z, v.w);
        }
        __syncthreads();
        const float* xrow = xs + b * XS_STRIDE;
        #pragma unroll 8
        for (int kk = 0; kk < KC; kk += 8) {
            float2 xa = *(const float2*)(xrow + kk);
            float2 xb = *(const float2*)(xrow + kk + 2);
            float2 xc = *(const float2*)(xrow + kk + 4);
            float2 xd = *(const float2*)(xrow + kk + 6);
            float4 wa = *(const float4*)(w1 + k0 + kk);
            float4 wb = *(const float4*)(w2 + k0 + kk);
            float4 wc = *(const float4*)(w1 + k0 + kk + 4);
            float4 wd = *(const float4*)(w2 + k0 + kk + 4);
            a1 += xa.x * wa.x + xa.y * wa.y + xb.x * wa.z + xb.y * wa.w;
            a2 += xa.x * wb.x + xa.y * wb.y + xb.x * wb.z + xb.y * wb.w;
            a3 += xc.x * wc.x + xc.y * wc.y + xd.x * wc.z + xd.y * wc.w;
            a4 += xc.x * wd.x + xc.y * wd.y + xd.x * wd.z + xd.y * wd.w;
        }
    }
    atomicAdd(&Y[(size_t)b * HIDDEN + o1], a1 + a3);
    atomicAdd(&Y[(size_t)b * HIDDEN + o2], a2 + a4);
}

// single-matrix projection (out-proj): grid = 256 * KSPLIT
__global__ __launch_bounds__(256, 4) void proj_kernel(const float* __restrict__ X,
                                                      const float* __restrict__ W,
                                                      float* __restrict__ Y) {
    proj_body(X, W, Y, blockIdx.x >> 2, blockIdx.x & 3);
}

// fused q+v projection: grid = 2 * 256 * KSPLIT, bit0 selects matrix
__global__ __launch_bounds__(256, 4) void proj_dual_kernel(const float* __restrict__ X,
                                                           const float* __restrict__ Wa,
                                                           const float* __restrict__ Wb,
                                                           float* __restrict__ Ya,
                                                           float* __restrict__ Yb) {
    const int bx = blockIdx.x;
    const float* W = (bx & 1) ? Wb : Wa;
    float* Y = (bx & 1) ? Yb : Ya;
    proj_body(X, W, Y, bx >> 3, (bx >> 1) & 3);
}

// ---------------------------------------------------------------------------
// Cache attention per (b,h): 512 threads = 8 waves, 64 keys per wave.
// Scores: float4 loads, 2 keys per wave-instr (half-wave split), 4 keys'
// reduction chains interleaved for ILP. PV: float4, fold halves via shfl 32.
// Fuses + v_new (softmax over single new key == 1 -> new_out = v_new).
// ---------------------------------------------------------------------------
__global__ __launch_bounds__(512, 6) void attn_kernel(const float* __restrict__ q,    // [32][4096]
                                                      const float* __restrict__ kc,   // [32][32][512][128]
                                                      const float* __restrict__ vc,
                                                      const float* __restrict__ vnew, // [32][4096]
                                                      float* __restrict__ attn_out) { // [32][4096]
    __shared__ float sc[CLEN];
    __shared__ float red[16];
    __shared__ float part[8 * HDIM];
    const int t = threadIdx.x;
    const int w = t >> 6;
    const int l = t & 63;
    const int bh = blockIdx.x;
    const int b = bh >> 5, h = bh & 31;
    const float* K = kc + (size_t)bh * CLEN * HDIM;
    const float* V = vc + (size_t)bh * CLEN * HDIM;
    const float scale = 0.088388347648318447f;   // 1/sqrt(128)
    const int d0 = 4 * (l & 31);
    const int kh = l >> 5;                        // half-wave: key parity
    const size_t hoff = (size_t)b * HIDDEN + h * HDIM;
    float4 q4 = *(const float4*)(q + hoff + d0);

    // ---- scores: keys [w*64, w*64+64), 8 keys per iteration ----
    const int kbeg = w * 64;
    #pragma unroll 2
    for (int k = kbeg; k < kbeg + 64; k += 8) {
        float4 k0v = *(const float4*)(K + (size_t)(k + 0 + kh) * HDIM + d0);
        float4 k1v = *(const float4*)(K + (size_t)(k + 2 + kh) * HDIM + d0);
        float4 k2v = *(const float4*)(K + (size_t)(k + 4 + kh) * HDIM + d0);
        float4 k3v = *(const float4*)(K + (size_t)(k + 6 + kh) * HDIM + d0);
        float p0 = q4.x * k0v.x + q4.y * k0v.y + q4.z * k0v.z + q4.w * k0v.w;
        float p1 = q4.x * k1v.x + q4.y * k1v.y + q4.z * k1v.z + q4.w * k1v.w;
        float p2 = q4.x * k2v.x + q4.y * k2v.y + q4.z * k2v.z + q4.w * k2v.w;
        float p3 = q4.x * k3v.x + q4.y * k3v.y + q4.z * k3v.z + q4.w * k3v.w;
        #pragma unroll
        for (int m = 16; m; m >>= 1) {       // reduce within each 32-lane half
            p0 += __shfl_xor(p0, m);
            p1 += __shfl_xor(p1, m);
            p2 += __shfl_xor(p2, m);
            p3 += __shfl_xor(p3, m);
        }
        if ((l & 31) == 0) {
            sc[k + 0 + kh] = p0 * scale;
            sc[k + 2 + kh] = p1 * scale;
            sc[k + 4 + kh] = p2 * scale;
            sc[k + 6 + kh] = p3 * scale;
        }
    }
    __syncthreads();

    // ---- softmax: one score per thread ----
    float s = sc[t];
    float mx = s;
    #pragma unroll
    for (int m = 32; m; m >>= 1) mx = fmaxf(mx, __shfl_xor(mx, m));
    if (l == 0) red[w] = mx;
    __syncthreads();
    mx = fmaxf(fmaxf(fmaxf(red[0], red[1]), fmaxf(red[2], red[3])),
               fmaxf(fmaxf(red[4], red[5]), fmaxf(red[6], red[7])));
    float e = __expf(s - mx);
    sc[t] = e;
    float es = e;
    #pragma unroll
    for (int m = 32; m; m >>= 1) es += __shfl_xor(es, m);
    if (l == 0) red[8 + w] = es;
    __syncthreads();
    const float inv = 1.0f / (red[8] + red[9] + red[10] + red[11] +
                              red[12] + red[13] + red[14] + red[15]);

    // ---- PV: same key range, float4, 2 keys per wave-instr ----
    float4 acc = make_float4(0.f, 0.f, 0.f, 0.f);
    #pragma unroll 4
    for (int k = kbeg; k < kbeg + 64; k += 2) {
        float4 v4 = *(const float4*)(V + (size_t)(k + kh) * HDIM + d0);
        float p = sc[k + kh];
        acc.x += p * v4.x; acc.y += p * v4.y;
        acc.z += p * v4.z; acc.w += p * v4.w;
    }
    acc.x += __shfl_xor(acc.x, 32);
    acc.y += __shfl_xor(acc.y, 32);
    acc.z += __shfl_xor(acc.z, 32);
    acc.w += __shfl_xor(acc.w, 32);
    if (l < 32) *(float4*)(&part[w * HDIM + d0]) = acc;
    __syncthreads();
    if (t < HDIM) {
        float r = 0.f;
        #pragma unroll
        for (int ww = 0; ww < 8; ++ww) r += part[ww * HDIM + t];
        attn_out[hoff + t] = r * inv + vnew[hoff + t];
    }
}

extern "C" void kernel_launch(void* const* d_in, const int* in_sizes, int n_in,
                              void* d_out, int out_size, void* d_ws, size_t ws_size,
                              hipStream_t stream) {
    (void)in_sizes; (void)n_in; (void)out_size; (void)ws_size;
    const float* x  = (const float*)d_in[0];
    const float* kc = (const float*)d_in[1];
    const float* vc = (const float*)d_in[2];
    const float* wq = (const float*)d_in[3];
    // d_in[4] (wk) unused: softmax over a single new key is exactly 1.0
    const float* wv = (const float*)d_in[5];
    const float* wo = (const float*)d_in[6];
    float* out = (float*)d_out;

    float* q    = (float*)d_ws;                 // 32*4096 fp32
    float* vnew = q + BATCH * HIDDEN;           // 32*4096 fp32
    float* attn = vnew + BATCH * HIDDEN;        // 32*4096 fp32

    // zero atomicAdd targets (q, vnew contiguous; d_out separately)
    hipMemsetAsync(d_ws, 0, 2 * BATCH * HIDDEN * sizeof(float), stream);
    hipMemsetAsync(d_out, 0, BATCH * HIDDEN * sizeof(float), stream);

    proj_dual_kernel<<<2 * 256 * KSPLIT, 256, 0, stream>>>(x, wq, wv, q, vnew);
    attn_kernel<<<BATCH * NHEADS, 512, 0, stream>>>(q, kc, vc, vnew, attn);
    proj_kernel<<<256 * KSPLIT, 256, 0, stream>>>(attn, wo, out);
}

// Round 3
// 205.254 us; speedup vs baseline: 2.7211x; 1.9962x over previous
//
#include <hip/hip_runtime.h>
#include <hip/hip_bf16.h>

#define HIDDEN 4096
#define NHEADS 32
#define HDIM 128
#define CLEN 512
#define BATCH 32

// ---------------------------------------------------------------------------
// Projection: Y[b][o] = sum_k X[b][k] * W[o][k]   (X: [32][4096], W row-major)
// Register-blocked SGEMV, coalesced W streaming:
//   block = 512 threads = 8 waves. Block owns 8 W rows (rowbase..rowbase+7).
//   wave wid owns batch quartet b = wid*4..wid*4+3 (8 waves cover all 32 b).
//   lane l owns k-positions kp + 4*l (float4), kp stepping by 256.
//   Per iter: 8 W float4 loads (lane-coalesced: 64 lanes x 16B = 1KB/row
//   contiguous), 4 x float4 loads (L2-resident, 512KB total), 128 v_fma.
//   -> W streams at >=16 B/cyc/CU with 2+ waves/SIMD: HBM-bound by design.
//   No LDS, no barriers, no atomics. End: 6-step shuffle butterfly reduces
//   acc[8][4] across the 64 lanes' k-subsets; lane l>>1 stores output (l&1==0).
// ---------------------------------------------------------------------------
__device__ __forceinline__ void proj_body(const float* __restrict__ X,
                                          const float* __restrict__ W,
                                          float* __restrict__ Y,
                                          int rowblock) {
    const int t   = threadIdx.x;
    const int l   = t & 63;
    const int wid = t >> 6;                      // 0..7 -> batch quartet
    const int rowbase = rowblock * 8;
    const float* wp = W + (size_t)rowbase * HIDDEN + 4 * l;
    const float* xp = X + (size_t)(wid * 4) * HIDDEN + 4 * l;

    float v[32];
    #pragma unroll
    for (int j = 0; j < 32; ++j) v[j] = 0.f;

    #pragma unroll 2
    for (int kp = 0; kp < HIDDEN; kp += 256) {
        float4 wv[8], xv[4];
        #pragma unroll
        for (int r = 0; r < 8; ++r)
            wv[r] = *(const float4*)(wp + (size_t)r * HIDDEN + kp);
        #pragma unroll
        for (int b = 0; b < 4; ++b)
            xv[b] = *(const float4*)(xp + (size_t)b * HIDDEN + kp);
        #pragma unroll
        for (int r = 0; r < 8; ++r) {
            #pragma unroll
            for (int b = 0; b < 4; ++b) {
                v[r * 4 + b] += wv[r].x * xv[b].x + wv[r].y * xv[b].y +
                                wv[r].z * xv[b].z + wv[r].w * xv[b].w;
            }
        }
    }

    // ---- cross-lane reduction: 64 lanes hold partials of 32 outputs ----
    // pair-reduce (lanes l, l^1 become identical)
    #pragma unroll
    for (int j = 0; j < 32; ++j) v[j] += __shfl_xor(v[j], 1);
    // 5 halving steps: after step s, v[i] = out(i*2^s + ((l>>1)&(2^s-1)))
    #pragma unroll
    for (int s = 1; s <= 5; ++s) {
        const int m = 1 << s;
        const int bit = (l >> s) & 1;
        #pragma unroll
        for (int i = 0; i < (32 >> s); ++i) {
            float t0 = __shfl_xor(v[2 * i], m);
            float t1 = __shfl_xor(v[2 * i + 1], m);
            v[i] = bit ? (v[2 * i + 1] + t1) : (v[2 * i] + t0);
        }
    }
    if (!(l & 1)) {
        const int j = l >> 1;                    // output index 0..31
        const int r = j >> 2, b = j & 3;
        Y[(size_t)(wid * 4 + b) * HIDDEN + rowbase + r] = v[0];
    }
}

// fused q+v projection: grid = 2 * (4096/8); bit0 selects matrix
__global__ __launch_bounds__(512, 2) void proj_dual_kernel(const float* __restrict__ X,
                                                           const float* __restrict__ Wa,
                                                           const float* __restrict__ Wb,
                                                           float* __restrict__ Ya,
                                                           float* __restrict__ Yb) {
    const int bx = blockIdx.x;
    proj_body(X, (bx & 1) ? Wb : Wa, (bx & 1) ? Yb : Ya, bx >> 1);
}

// single-matrix projection (out-proj): grid = 4096/8
__global__ __launch_bounds__(512, 2) void proj_out_kernel(const float* __restrict__ X,
                                                          const float* __restrict__ W,
                                                          float* __restrict__ Y) {
    proj_body(X, W, Y, blockIdx.x);
}

// ---------------------------------------------------------------------------
// Cache attention per (b,h): 512 threads = 8 waves, 64 keys per wave.
// Scores: float4 loads, 2 keys per wave-instr (half-wave split), 4 keys'
// reduction chains interleaved for ILP. PV: float4, fold halves via shfl 32.
// Fuses + v_new (softmax over single new key == 1 -> new_out = v_new).
// ---------------------------------------------------------------------------
__global__ __launch_bounds__(512, 6) void attn_kernel(const float* __restrict__ q,    // [32][4096]
                                                      const float* __restrict__ kc,   // [32][32][512][128]
                                                      const float* __restrict__ vc,
                                                      const float* __restrict__ vnew, // [32][4096]
                                                      float* __restrict__ attn_out) { // [32][4096]
    __shared__ float sc[CLEN];
    __shared__ float red[16];
    __shared__ float part[8 * HDIM];
    const int t = threadIdx.x;
    const int w = t >> 6;
    const int l = t & 63;
    const int bh = blockIdx.x;
    const int b = bh >> 5, h = bh & 31;
    const float* K = kc + (size_t)bh * CLEN * HDIM;
    const float* V = vc + (size_t)bh * CLEN * HDIM;
    const float scale = 0.088388347648318447f;   // 1/sqrt(128)
    const int d0 = 4 * (l & 31);
    const int kh = l >> 5;                        // half-wave: key parity
    const size_t hoff = (size_t)b * HIDDEN + h * HDIM;
    float4 q4 = *(const float4*)(q + hoff + d0);

    // ---- scores: keys [w*64, w*64+64), 8 keys per iteration ----
    const int kbeg = w * 64;
    #pragma unroll 2
    for (int k = kbeg; k < kbeg + 64; k += 8) {
        float4 k0v = *(const float4*)(K + (size_t)(k + 0 + kh) * HDIM + d0);
        float4 k1v = *(const float4*)(K + (size_t)(k + 2 + kh) * HDIM + d0);
        float4 k2v = *(const float4*)(K + (size_t)(k + 4 + kh) * HDIM + d0);
        float4 k3v = *(const float4*)(K + (size_t)(k + 6 + kh) * HDIM + d0);
        float p0 = q4.x * k0v.x + q4.y * k0v.y + q4.z * k0v.z + q4.w * k0v.w;
        float p1 = q4.x * k1v.x + q4.y * k1v.y + q4.z * k1v.z + q4.w * k1v.w;
        float p2 = q4.x * k2v.x + q4.y * k2v.y + q4.z * k2v.z + q4.w * k2v.w;
        float p3 = q4.x * k3v.x + q4.y * k3v.y + q4.z * k3v.z + q4.w * k3v.w;
        #pragma unroll
        for (int m = 16; m; m >>= 1) {       // reduce within each 32-lane half
            p0 += __shfl_xor(p0, m);
            p1 += __shfl_xor(p1, m);
            p2 += __shfl_xor(p2, m);
            p3 += __shfl_xor(p3, m);
        }
        if ((l & 31) == 0) {
            sc[k + 0 + kh] = p0 * scale;
            sc[k + 2 + kh] = p1 * scale;
            sc[k + 4 + kh] = p2 * scale;
            sc[k + 6 + kh] = p3 * scale;
        }
    }
    __syncthreads();

    // ---- softmax: one score per thread ----
    float s = sc[t];
    float mx = s;
    #pragma unroll
    for (int m = 32; m; m >>= 1) mx = fmaxf(mx, __shfl_xor(mx, m));
    if (l == 0) red[w] = mx;
    __syncthreads();
    mx = fmaxf(fmaxf(fmaxf(red[0], red[1]), fmaxf(red[2], red[3])),
               fmaxf(fmaxf(red[4], red[5]), fmaxf(red[6], red[7])));
    float e = __expf(s - mx);
    sc[t] = e;
    float es = e;
    #pragma unroll
    for (int m = 32; m; m >>= 1) es += __shfl_xor(es, m);
    if (l == 0) red[8 + w] = es;
    __syncthreads();
    const float inv = 1.0f / (red[8] + red[9] + red[10] + red[11] +
                              red[12] + red[13] + red[14] + red[15]);

    // ---- PV: same key range, float4, 2 keys per wave-instr ----
    float4 acc = make_float4(0.f, 0.f, 0.f, 0.f);
    #pragma unroll 4
    for (int k = kbeg; k < kbeg + 64; k += 2) {
        float4 v4 = *(const float4*)(V + (size_t)(k + kh) * HDIM + d0);
        float p = sc[k + kh];
        acc.x += p * v4.x; acc.y += p * v4.y;
        acc.z += p * v4.z; acc.w += p * v4.w;
    }
    acc.x += __shfl_xor(acc.x, 32);
    acc.y += __shfl_xor(acc.y, 32);
    acc.z += __shfl_xor(acc.z, 32);
    acc.w += __shfl_xor(acc.w, 32);
    if (l < 32) *(float4*)(&part[w * HDIM + d0]) = acc;
    __syncthreads();
    if (t < HDIM) {
        float r = 0.f;
        #pragma unroll
        for (int ww = 0; ww < 8; ++ww) r += part[ww * HDIM + t];
        attn_out[hoff + t] = r * inv + vnew[hoff + t];
    }
}

extern "C" void kernel_launch(void* const* d_in, const int* in_sizes, int n_in,
                              void* d_out, int out_size, void* d_ws, size_t ws_size,
                              hipStream_t stream) {
    (void)in_sizes; (void)n_in; (void)out_size; (void)ws_size;
    const float* x  = (const float*)d_in[0];
    const float* kc = (const float*)d_in[1];
    const float* vc = (const float*)d_in[2];
    const float* wq = (const float*)d_in[3];
    // d_in[4] (wk) unused: softmax over a single new key is exactly 1.0
    const float* wv = (const float*)d_in[5];
    const float* wo = (const float*)d_in[6];
    float* out = (float*)d_out;

    float* q    = (float*)d_ws;                 // 32*4096 fp32
    float* vnew = q + BATCH * HIDDEN;           // 32*4096 fp32
    float* attn = vnew + BATCH * HIDDEN;        // 32*4096 fp32

    proj_dual_kernel<<<2 * (HIDDEN / 8), 512, 0, stream>>>(x, wq, wv, q, vnew);
    attn_kernel<<<BATCH * NHEADS, 512, 0, stream>>>(q, kc, vc, vnew, attn);
    proj_out_kernel<<<HIDDEN / 8, 512, 0, stream>>>(attn, wo, out);
}